// Round 4
// baseline (1939.511 us; speedup 1.0000x reference)
//
#include <hip/hip_runtime.h>
#include <hip/hip_bf16.h>
#include <math.h>

#define N_NODES 100000
#define N_EDGES 1200000
#define N_GRAPHS 512
#define NBIN 1563  // ceil(N_NODES/64)

typedef __bf16 bf16x8 __attribute__((ext_vector_type(8)));
typedef float f32x4 __attribute__((ext_vector_type(4)));

// ---- float <-> monotonic unsigned (for atomicMax on floats) ----
__device__ __forceinline__ unsigned f2ord(float f) {
  unsigned u = __float_as_uint(f);
  return (u & 0x80000000u) ? ~u : (u | 0x80000000u);
}
__device__ __forceinline__ float ord2f(unsigned u) {
  return (u & 0x80000000u) ? __uint_as_float(u & 0x7fffffffu) : __uint_as_float(~u);
}

__global__ void init_pool_kernel(float* gsum, unsigned* gmax, int* gcnt) {
  int i = blockIdx.x * blockDim.x + threadIdx.x;
  if (i < N_GRAPHS * 64) {
    gsum[i] = 0.0f;
    gmax[i] = 0x407FFFFFu;  // f2ord(-1.0f); elu outputs are > -1, safe identity
  }
  if (i < N_GRAPHS) gcnt[i] = 0;
}

// ---------------- bin-CSR build (64-node bins; shared by all 3 layers) ------
__global__ void hist_bins_kernel(const int* __restrict__ dst, int* __restrict__ binc) {
  int e = blockIdx.x * 256 + threadIdx.x;
  if (e < N_EDGES) atomicAdd(&binc[dst[e] >> 6], 1);
}

// single-block exclusive scan over NBIN bin counts (512 thr x 4 bins)
__global__ void scan_bins_kernel(const int* __restrict__ binc,
                                 int* __restrict__ boff, int* __restrict__ cursor) {
  __shared__ int s[512];
  int t = threadIdx.x;
  int v[4];
  int sum = 0;
#pragma unroll
  for (int i = 0; i < 4; ++i) {
    int b = t * 4 + i;
    v[i] = (b < NBIN) ? binc[b] : 0;
    sum += v[i];
  }
  s[t] = sum;
  __syncthreads();
  for (int o = 1; o < 512; o <<= 1) {
    int x = (t >= o) ? s[t - o] : 0;
    __syncthreads();
    s[t] += x;
    __syncthreads();
  }
  int excl = s[t] - sum;  // exclusive prefix of this thread's chunk
#pragma unroll
  for (int i = 0; i < 4; ++i) {
    int b = t * 4 + i;
    if (b < NBIN) {
      boff[b] = excl;
      cursor[b] = excl;
    }
    excl += v[i];
  }
  if (t == 0) boff[NBIN] = N_EDGES;
}

// elist entry: src | (local_row << 17)   (src < 2^17, row < 64)
__global__ void fill_bins_kernel(const int* __restrict__ src, const int* __restrict__ dst,
                                 int* __restrict__ cursor, int* __restrict__ elist) {
  int e = blockIdx.x * 256 + threadIdx.x;
  if (e < N_EDGES) {
    int d = dst[e];
    int p = atomicAdd(&cursor[d >> 6], 1);
    elist[p] = src[e] | ((d & 63) << 17);
  }
}

// ---------------- dense pipeline ---------------------------------------------
// h0 = x @ W_emb + b_emb   (x: [N,7], W: [7,64]) -> bf16
__global__ void embed_kernel(const float* __restrict__ x,
                             const float* __restrict__ W,
                             const float* __restrict__ b,
                             __bf16* __restrict__ h) {
  __shared__ float Ws[7 * 64];
  __shared__ float bs[64];
  int t = threadIdx.x;
  for (int i = t; i < 7 * 64; i += 256) Ws[i] = W[i];
  if (t < 64) bs[t] = b[t];
  __syncthreads();
  int gid = blockIdx.x * 256 + t;
  int n = gid >> 6, f = gid & 63;
  const float* xr = x + n * 7;
  float acc = bs[f];
#pragma unroll
  for (int k = 0; k < 7; ++k) acc = fmaf(xr[k], Ws[k * 64 + f], acc);
  h[gid] = (__bf16)acc;
}

// Pre-permute all 3 layers' f32 weights into bf16 MFMA B-fragment order.
__global__ void convert_all_kernel(const float* __restrict__ W1a, const float* __restrict__ W1b,
                                   const float* __restrict__ W2a, const float* __restrict__ W2b,
                                   const float* __restrict__ W3a, const float* __restrict__ W3b,
                                   __bf16* __restrict__ wp) {
  int o = blockIdx.x * 256 + threadIdx.x;  // 0..49151
  int L = o >> 14, q = o & 16383;
  const float* Wa = (L == 0) ? W1a : (L == 1) ? W2a : W3a;
  const float* Wb = (L == 0) ? W1b : (L == 1) ? W2b : W3b;
  if (q < 8192) {
    int j = q & 7, c = (q >> 3) & 15, kc = (q >> 7) & 3, kt = (q >> 9) & 1, nt = q >> 10;
    wp[o] = (__bf16)Wa[(kt * 32 + kc * 8 + j) * 128 + nt * 16 + c];
  } else {
    int p = q - 8192;
    int j = p & 7, c = (p >> 3) & 15, kc = (p >> 7) & 3, kt = (p >> 9) & 3, nt2 = p >> 11;
    wp[o] = (__bf16)Wb[(kt * 32 + kc * 8 + j) * 64 + nt2 * 16 + c];
  }
}

// Fused: bin-CSR gather (edge-parallel, LDS f32 atomics) + GIN MLP via MFMA.
// One block = 64 nodes (= one bin), 4 waves. LDS: single 17.4KB union buffer
// (f32 Ag[64][68] during gather; bf16 Hs[64][136] for the hidden tile).
__launch_bounds__(256)
__global__ void gin_fused2_kernel(const __bf16* __restrict__ hin,
                                  __bf16* __restrict__ hout,
                                  const int* __restrict__ boff,
                                  const int* __restrict__ elist,
                                  const float* __restrict__ eps_p,
                                  const __bf16* __restrict__ W1p,
                                  const float* __restrict__ b1,
                                  const __bf16* __restrict__ W2p,
                                  const float* __restrict__ b2) {
  __shared__ float Ag[64 * 68];           // 17408 B; reused as Hs[64][136] bf16
  __bf16* Hs = (__bf16*)Ag;
  int t = threadIdx.x, lane = t & 63, wv = t >> 6;
  int c = lane & 15, kc = lane >> 4;
  int m0 = wv * 16;
  float epsv = 1.0f + eps_p[0];
  int n0b = blockIdx.x * 64;

  // init Ag with the (1+eps)*h self term
  for (int r = wv; r < 64; r += 4) {
    int n = n0b + r;
    float v = (n < N_NODES) ? epsv * (float)hin[(size_t)n * 64 + lane] : 0.0f;
    Ag[r * 68 + lane] = v;
  }
  __syncthreads();

  // edge-parallel gather: all 4 waves stripe over this bin's edge list
  int e0 = boff[blockIdx.x], e1 = boff[blockIdx.x + 1];
  for (int base = e0 + wv * 64; base < e1; base += 256) {
    int cnt = min(64, e1 - base);
    int ev = (lane < cnt) ? elist[base + lane] : 0;
    int j = 0;
    for (; j + 8 <= cnt; j += 8) {
#pragma unroll
      for (int u = 0; u < 8; ++u) {
        int v = __shfl(ev, j + u);
        float f = (float)hin[(size_t)(v & 0x1FFFF) * 64 + lane];
        atomicAdd(&Ag[(v >> 17) * 68 + lane], f);
      }
    }
    for (; j < cnt; ++j) {
      int v = __shfl(ev, j);
      float f = (float)hin[(size_t)(v & 0x1FFFF) * 64 + lane];
      atomicAdd(&Ag[(v >> 17) * 68 + lane], f);
    }
  }
  __syncthreads();

  // A fragments (wave-own rows), f32 -> bf16
  bf16x8 a1_0, a1_1;
  {
    const float* rowp = &Ag[(m0 + c) * 68];
#pragma unroll
    for (int i = 0; i < 8; ++i) {
      a1_0[i] = (__bf16)rowp[kc * 8 + i];
      a1_1[i] = (__bf16)rowp[32 + kc * 8 + i];
    }
  }
  __syncthreads();  // everyone done reading Ag before Hs overwrites the union

  // GEMM1: [16x64] @ [64x128]
  f32x4 acc1[8];
#pragma unroll
  for (int nt = 0; nt < 8; ++nt) {
    float bv = b1[nt * 16 + c];
    f32x4 acc = {bv, bv, bv, bv};
    bf16x8 bf0 = *(const bf16x8*)&W1p[(nt * 2 + 0) * 512 + kc * 128 + c * 8];
    bf16x8 bf1 = *(const bf16x8*)&W1p[(nt * 2 + 1) * 512 + kc * 128 + c * 8];
    acc = __builtin_amdgcn_mfma_f32_16x16x32_bf16(a1_0, bf0, acc, 0, 0, 0);
    acc = __builtin_amdgcn_mfma_f32_16x16x32_bf16(a1_1, bf1, acc, 0, 0, 0);
    acc1[nt] = acc;
  }
  // relu -> bf16 hidden tile (wave-private rows; per-wave DS ordering suffices)
#pragma unroll
  for (int nt = 0; nt < 8; ++nt) {
#pragma unroll
    for (int r = 0; r < 4; ++r) {
      Hs[(m0 + kc * 4 + r) * 136 + nt * 16 + c] = (__bf16)fmaxf(acc1[nt][r], 0.0f);
    }
  }

  // GEMM2: [16x128] @ [128x64]
  bf16x8 a2[4];
#pragma unroll
  for (int kt = 0; kt < 4; ++kt)
    a2[kt] = *(const bf16x8*)&Hs[(m0 + c) * 136 + kt * 32 + kc * 8];
#pragma unroll
  for (int nt2 = 0; nt2 < 4; ++nt2) {
    float bv = b2[nt2 * 16 + c];
    f32x4 acc = {bv, bv, bv, bv};
#pragma unroll
    for (int kt = 0; kt < 4; ++kt) {
      bf16x8 bf = *(const bf16x8*)&W2p[(nt2 * 4 + kt) * 512 + kc * 128 + c * 8];
      acc = __builtin_amdgcn_mfma_f32_16x16x32_bf16(a2[kt], bf, acc, 0, 0, 0);
    }
#pragma unroll
    for (int r = 0; r < 4; ++r) {
      int g = n0b + m0 + kc * 4 + r;
      if (g < N_NODES) {
        float o = acc[r];
        hout[(size_t)g * 64 + nt2 * 16 + c] = (__bf16)((o > 0.0f) ? o : expm1f(o));
      }
    }
  }
}

// per-graph sum/max/count; batch sorted -> wave scans contiguous chunk
__global__ void pool_kernel(const __bf16* __restrict__ h,
                            const int* __restrict__ batch,
                            float* gsum, unsigned* gmax, int* gcnt) {
  int lane = threadIdx.x & 63;
  int wave = (blockIdx.x * blockDim.x + threadIdx.x) >> 6;
  int nwaves = (gridDim.x * blockDim.x) >> 6;
  int chunk = (N_NODES + nwaves - 1) / nwaves;
  int n0 = wave * chunk;
  int n1 = min(n0 + chunk, N_NODES);
  if (n0 >= N_NODES) return;
  int cur = batch[n0];
  float s = 0.0f, m = -2.0f;
  int cnt = 0;
  for (int n = n0; n < n1; ++n) {
    int g = batch[n];
    if (g != cur) {
      atomicAdd(&gsum[cur * 64 + lane], s);
      atomicMax(&gmax[cur * 64 + lane], f2ord(m));
      if (lane == 0) atomicAdd(&gcnt[cur], cnt);
      cur = g; s = 0.0f; m = -2.0f; cnt = 0;
    }
    float v = (float)h[(size_t)n * 64 + lane];
    s += v;
    m = fmaxf(m, v);
    ++cnt;
  }
  atomicAdd(&gsum[cur * 64 + lane], s);
  atomicMax(&gmax[cur * 64 + lane], f2ord(m));
  if (lane == 0) atomicAdd(&gcnt[cur], cnt);
}

// out = relu([mean|max] @ Wc1 + bc1) @ Wc2 + bc2 ; one 64-thread block / graph
__global__ void cls_kernel(const float* __restrict__ gsum,
                           const unsigned* __restrict__ gmax,
                           const int* __restrict__ gcnt,
                           const float* __restrict__ Wc1,
                           const float* __restrict__ bc1,
                           const float* __restrict__ Wc2,
                           const float* __restrict__ bc2,
                           float* __restrict__ out) {
  __shared__ float gv[128];
  __shared__ float tv[64];
  int g = blockIdx.x, l = threadIdx.x;
  float cnt = fmaxf((float)gcnt[g], 1.0f);
  gv[l] = gsum[g * 64 + l] / cnt;
  gv[64 + l] = ord2f(gmax[g * 64 + l]);
  __syncthreads();
  float acc = bc1[l];
#pragma unroll 8
  for (int k = 0; k < 128; ++k) acc = fmaf(gv[k], Wc1[k * 64 + l], acc);
  tv[l] = fmaxf(acc, 0.0f);
  __syncthreads();
  if (l < 10) {
    float o = bc2[l];
#pragma unroll
    for (int k = 0; k < 64; ++k) o = fmaf(tv[k], Wc2[k * 10 + l], o);
    out[g * 10 + l] = o;
  }
}

extern "C" void kernel_launch(void* const* d_in, const int* in_sizes, int n_in,
                              void* d_out, int out_size, void* d_ws, size_t ws_size,
                              hipStream_t stream) {
  const float* x     = (const float*)d_in[0];
  const int*   ei    = (const int*)d_in[1];
  const int*   batch = (const int*)d_in[2];
  const float* W_emb = (const float*)d_in[3];
  const float* b_emb = (const float*)d_in[4];
  const float* eps1  = (const float*)d_in[5];
  const float* W1a   = (const float*)d_in[6];
  const float* b1a   = (const float*)d_in[7];
  const float* W1b   = (const float*)d_in[8];
  const float* b1b   = (const float*)d_in[9];
  const float* eps2  = (const float*)d_in[10];
  const float* W2a   = (const float*)d_in[11];
  const float* b2a   = (const float*)d_in[12];
  const float* W2b   = (const float*)d_in[13];
  const float* b2b   = (const float*)d_in[14];
  const float* eps3  = (const float*)d_in[15];
  const float* W3a   = (const float*)d_in[16];
  const float* b3a   = (const float*)d_in[17];
  const float* W3b   = (const float*)d_in[18];
  const float* b3b   = (const float*)d_in[19];
  const float* Wc1   = (const float*)d_in[20];
  const float* bc1   = (const float*)d_in[21];
  const float* Wc2   = (const float*)d_in[22];
  const float* bc2   = (const float*)d_in[23];
  float* out = (float*)d_out;

  // workspace layout (byte-based)
  char* w = (char*)d_ws;
  __bf16*   h0   = (__bf16*)w;                     w += (size_t)N_NODES * 64 * 2;  // 12.8MB
  __bf16*   h1   = (__bf16*)w;                     w += (size_t)N_NODES * 64 * 2;  // 12.8MB
  float*    gsum = (float*)w;                      w += N_GRAPHS * 64 * 4;
  unsigned* gmax = (unsigned*)w;                   w += N_GRAPHS * 64 * 4;
  int*      gcnt = (int*)w;                        w += N_GRAPHS * 4;
  __bf16*   wp   = (__bf16*)w;                     w += 3 * 16384 * 2;
  int*      binc = (int*)w;                        w += 6272;
  int*      boff = (int*)w;                        w += 6272;
  int*      curw = (int*)w;                        w += 6272;
  int*      elist= (int*)w;                        w += (size_t)N_EDGES * 4;      // 4.8MB

  const int* src = ei;             // edge_index[0]
  const int* dst = ei + N_EDGES;   // edge_index[1]

  const float* epss[3] = {eps1, eps2, eps3};
  const float* bas[3]  = {b1a, b2a, b3a};
  const float* bbs[3]  = {b1b, b2b, b3b};

  const int EB = (N_EDGES + 255) / 256;

  // bin-CSR build (edge list identical for all 3 layers)
  hipMemsetAsync(binc, 0, NBIN * sizeof(int), stream);
  hist_bins_kernel<<<EB, 256, 0, stream>>>(dst, binc);
  scan_bins_kernel<<<1, 512, 0, stream>>>(binc, boff, curw);
  fill_bins_kernel<<<EB, 256, 0, stream>>>(src, dst, curw, elist);

  init_pool_kernel<<<(N_GRAPHS * 64 + 255) / 256, 256, 0, stream>>>(gsum, gmax, gcnt);
  convert_all_kernel<<<192, 256, 0, stream>>>(W1a, W1b, W2a, W2b, W3a, W3b, wp);
  embed_kernel<<<(N_NODES * 64) / 256, 256, 0, stream>>>(x, W_emb, b_emb, h0);

  __bf16* hbuf[4] = {h0, h1, h0, h1};
  for (int L = 0; L < 3; ++L) {
    gin_fused2_kernel<<<NBIN, 256, 0, stream>>>(
        hbuf[L], hbuf[L + 1], boff, elist, epss[L],
        wp + (size_t)L * 16384, bas[L],
        wp + (size_t)L * 16384 + 8192, bbs[L]);
  }

  pool_kernel<<<512, 256, 0, stream>>>(h1, batch, gsum, gmax, gcnt);
  cls_kernel<<<N_GRAPHS, 64, 0, stream>>>(gsum, gmax, gcnt, Wc1, bc1, Wc2, bc2, out);
}

// Round 5
// 505.536 us; speedup vs baseline: 3.8365x; 3.8365x over previous
//
#include <hip/hip_runtime.h>
#include <hip/hip_bf16.h>
#include <math.h>

#define N_NODES 100000
#define N_EDGES 1200000
#define N_GRAPHS 512

typedef __bf16 bf16x8 __attribute__((ext_vector_type(8)));
typedef float f32x4 __attribute__((ext_vector_type(4)));

// ---- float <-> monotonic unsigned (for atomicMax on floats) ----
__device__ __forceinline__ unsigned f2ord(float f) {
  unsigned u = __float_as_uint(f);
  return (u & 0x80000000u) ? ~u : (u | 0x80000000u);
}
__device__ __forceinline__ float ord2f(unsigned u) {
  return (u & 0x80000000u) ? __uint_as_float(u & 0x7fffffffu) : __uint_as_float(~u);
}

// ---------------- per-node CSR build (verbatim round 3; proven) -------------
__global__ void hist_kernel(const int* __restrict__ dst, int* __restrict__ deg) {
  int e = blockIdx.x * 256 + threadIdx.x;
  if (e < N_EDGES) atomicAdd(&deg[dst[e]], 1);
}

__global__ void scan_sums_kernel(const int* __restrict__ deg, int* __restrict__ bsum) {
  __shared__ int s[256];
  int t = threadIdx.x;
  int i = blockIdx.x * 256 + t;
  s[t] = (i < N_NODES) ? deg[i] : 0;
  __syncthreads();
  for (int o = 128; o > 0; o >>= 1) {
    if (t < o) s[t] += s[t + o];
    __syncthreads();
  }
  if (t == 0) bsum[blockIdx.x] = s[0];
}

__global__ void scan_bsums_kernel(const int* __restrict__ bsum, int* __restrict__ boff,
                                  int nb) {
  __shared__ int s[512];
  int t = threadIdx.x;
  int own = (t < nb) ? bsum[t] : 0;
  s[t] = own;
  __syncthreads();
  for (int o = 1; o < 512; o <<= 1) {
    int v = (t >= o) ? s[t - o] : 0;
    __syncthreads();
    s[t] += v;
    __syncthreads();
  }
  if (t < nb) boff[t] = s[t] - own;  // exclusive
}

__global__ void scan_final_kernel(const int* __restrict__ deg,
                                  const int* __restrict__ boff,
                                  int* __restrict__ row_ptr,
                                  int* __restrict__ curw) {
  __shared__ int s[256];
  int t = threadIdx.x;
  int i = blockIdx.x * 256 + t;
  int own = (i < N_NODES) ? deg[i] : 0;
  s[t] = own;
  __syncthreads();
  for (int o = 1; o < 256; o <<= 1) {
    int v = (t >= o) ? s[t - o] : 0;
    __syncthreads();
    s[t] += v;
    __syncthreads();
  }
  if (i < N_NODES) {
    int excl = boff[blockIdx.x] + s[t] - own;
    row_ptr[i] = excl;
    curw[i] = excl;
  }
  if (i == 0) row_ptr[N_NODES] = N_EDGES;
}

__global__ void fill_csr_kernel(const int* __restrict__ src, const int* __restrict__ dst,
                                int* __restrict__ curw, int* __restrict__ ssrc) {
  int e = blockIdx.x * 256 + threadIdx.x;
  if (e < N_EDGES) {
    int p = atomicAdd(&curw[dst[e]], 1);
    ssrc[p] = src[e];
  }
}

// ---------------- dense pipeline ---------------------------------------------
// h0 = x @ W_emb + b_emb   (x: [N,7], W: [7,64]) -> bf16
__global__ void embed_kernel(const float* __restrict__ x,
                             const float* __restrict__ W,
                             const float* __restrict__ b,
                             __bf16* __restrict__ h) {
  __shared__ float Ws[7 * 64];
  __shared__ float bs[64];
  int t = threadIdx.x;
  for (int i = t; i < 7 * 64; i += 256) Ws[i] = W[i];
  if (t < 64) bs[t] = b[t];
  __syncthreads();
  int gid = blockIdx.x * 256 + t;
  int n = gid >> 6, f = gid & 63;
  const float* xr = x + n * 7;
  float acc = bs[f];
#pragma unroll
  for (int k = 0; k < 7; ++k) acc = fmaf(xr[k], Ws[k * 64 + f], acc);
  h[gid] = (__bf16)acc;
}

// Pre-permute all 3 layers' weights into bf16 MFMA B-fragment order;
// also folds the pool-accumulator init (saves a launch).
__global__ void convert_all_kernel(const float* __restrict__ W1a, const float* __restrict__ W1b,
                                   const float* __restrict__ W2a, const float* __restrict__ W2b,
                                   const float* __restrict__ W3a, const float* __restrict__ W3b,
                                   __bf16* __restrict__ wp,
                                   float* gsum, unsigned* gmax, int* gcnt) {
  int o = blockIdx.x * 256 + threadIdx.x;  // 0..49151
  if (o < N_GRAPHS * 64) {
    gsum[o] = 0.0f;
    gmax[o] = 0x407FFFFFu;  // f2ord(-1.0f); elu outputs > -1, safe identity
  }
  if (o < N_GRAPHS) gcnt[o] = 0;
  int L = o >> 14, q = o & 16383;
  const float* Wa = (L == 0) ? W1a : (L == 1) ? W2a : W3a;
  const float* Wb = (L == 0) ? W1b : (L == 1) ? W2b : W3b;
  if (q < 8192) {
    int j = q & 7, c = (q >> 3) & 15, kc = (q >> 7) & 3, kt = (q >> 9) & 1, nt = q >> 10;
    wp[o] = (__bf16)Wa[(kt * 32 + kc * 8 + j) * 128 + nt * 16 + c];
  } else {
    int p = q - 8192;
    int j = p & 7, c = (p >> 3) & 15, kc = (p >> 7) & 3, kt = (p >> 9) & 3, nt2 = p >> 11;
    wp[o] = (__bf16)Wb[(kt * 32 + kc * 8 + j) * 64 + nt2 * 16 + c];
  }
}

// Fused: CSR gather (row-serial register accumulation, dual-row interleave,
// scalar src indices) + GIN MLP via MFMA. One block = 64 nodes, 4 waves;
// each wave owns rows wv*16..+15 end-to-end -> NO __syncthreads.
__launch_bounds__(256)
__global__ void gin_fused3_kernel(const __bf16* __restrict__ hin,
                                  __bf16* __restrict__ hout,
                                  const int* __restrict__ row_ptr,
                                  const int* __restrict__ ssrc,
                                  const float* __restrict__ eps_p,
                                  const __bf16* __restrict__ W1p,
                                  const float* __restrict__ b1,
                                  const __bf16* __restrict__ W2p,
                                  const float* __restrict__ b2) {
  __shared__ __bf16 As[64 * 72];
  __shared__ __bf16 Hs[64 * 136];
  int t = threadIdx.x, lane = t & 63, wv = t >> 6;
  int c = lane & 15, kc = lane >> 4;
  int m0 = wv * 16;
  float epsv = 1.0f + eps_p[0];
  int n0b = blockIdx.x * 64;
  int n0w = n0b + m0;

  // row_ptr[n0w .. n0w+16] via lanes 0..16
  int rp = row_ptr[min(n0w + min(lane, 16), N_NODES)];

  // dual-stream gather: rows (rr, rr+8) with 8 loads in flight
  for (int rr = 0; rr < 8; ++rr) {
    int rA = rr, rB = rr + 8;
    int nA = n0w + rA, nB = n0w + rB;
    int jA = __builtin_amdgcn_readfirstlane(__shfl(rp, rA));
    int eA = __builtin_amdgcn_readfirstlane(__shfl(rp, rA + 1));
    int jB = __builtin_amdgcn_readfirstlane(__shfl(rp, rB));
    int eB = __builtin_amdgcn_readfirstlane(__shfl(rp, rB + 1));
    float accA = (nA < N_NODES) ? epsv * (float)hin[(size_t)nA * 64 + lane] : 0.0f;
    float accB = (nB < N_NODES) ? epsv * (float)hin[(size_t)nB * 64 + lane] : 0.0f;
    while (jA + 4 <= eA && jB + 4 <= eB) {
      int a0 = ssrc[jA], a1 = ssrc[jA + 1], a2 = ssrc[jA + 2], a3 = ssrc[jA + 3];
      int b0 = ssrc[jB], b1_ = ssrc[jB + 1], b2_ = ssrc[jB + 2], b3_ = ssrc[jB + 3];
      float fa0 = (float)hin[(size_t)a0 * 64 + lane];
      float fa1 = (float)hin[(size_t)a1 * 64 + lane];
      float fa2 = (float)hin[(size_t)a2 * 64 + lane];
      float fa3 = (float)hin[(size_t)a3 * 64 + lane];
      float fb0 = (float)hin[(size_t)b0 * 64 + lane];
      float fb1 = (float)hin[(size_t)b1_ * 64 + lane];
      float fb2 = (float)hin[(size_t)b2_ * 64 + lane];
      float fb3 = (float)hin[(size_t)b3_ * 64 + lane];
      accA += (fa0 + fa1) + (fa2 + fa3);
      accB += (fb0 + fb1) + (fb2 + fb3);
      jA += 4; jB += 4;
    }
    for (; jA + 4 <= eA; jA += 4) {
      int a0 = ssrc[jA], a1 = ssrc[jA + 1], a2 = ssrc[jA + 2], a3 = ssrc[jA + 3];
      float f0 = (float)hin[(size_t)a0 * 64 + lane];
      float f1 = (float)hin[(size_t)a1 * 64 + lane];
      float f2 = (float)hin[(size_t)a2 * 64 + lane];
      float f3 = (float)hin[(size_t)a3 * 64 + lane];
      accA += (f0 + f1) + (f2 + f3);
    }
    for (; jB + 4 <= eB; jB += 4) {
      int b0 = ssrc[jB], b1v = ssrc[jB + 1], b2v = ssrc[jB + 2], b3v = ssrc[jB + 3];
      float f0 = (float)hin[(size_t)b0 * 64 + lane];
      float f1 = (float)hin[(size_t)b1v * 64 + lane];
      float f2 = (float)hin[(size_t)b2v * 64 + lane];
      float f3 = (float)hin[(size_t)b3v * 64 + lane];
      accB += (f0 + f1) + (f2 + f3);
    }
    for (; jA < eA; ++jA) accA += (float)hin[(size_t)ssrc[jA] * 64 + lane];
    for (; jB < eB; ++jB) accB += (float)hin[(size_t)ssrc[jB] * 64 + lane];
    As[(m0 + rA) * 72 + lane] = (__bf16)accA;
    As[(m0 + rB) * 72 + lane] = (__bf16)accB;
  }

  // GEMM1: [16x64] @ [64x128]  (wave-private rows)
  bf16x8 a1_0 = *(const bf16x8*)&As[(m0 + c) * 72 + 0 * 32 + kc * 8];
  bf16x8 a1_1 = *(const bf16x8*)&As[(m0 + c) * 72 + 1 * 32 + kc * 8];
  f32x4 acc1[8];
#pragma unroll
  for (int nt = 0; nt < 8; ++nt) {
    float bv = b1[nt * 16 + c];
    f32x4 acc = {bv, bv, bv, bv};
    bf16x8 bf0 = *(const bf16x8*)&W1p[(nt * 2 + 0) * 512 + kc * 128 + c * 8];
    bf16x8 bf1 = *(const bf16x8*)&W1p[(nt * 2 + 1) * 512 + kc * 128 + c * 8];
    acc = __builtin_amdgcn_mfma_f32_16x16x32_bf16(a1_0, bf0, acc, 0, 0, 0);
    acc = __builtin_amdgcn_mfma_f32_16x16x32_bf16(a1_1, bf1, acc, 0, 0, 0);
    acc1[nt] = acc;
  }
  // relu -> bf16 hidden tile (wave-private rows)
#pragma unroll
  for (int nt = 0; nt < 8; ++nt) {
#pragma unroll
    for (int r = 0; r < 4; ++r) {
      Hs[(m0 + kc * 4 + r) * 136 + nt * 16 + c] = (__bf16)fmaxf(acc1[nt][r], 0.0f);
    }
  }

  // GEMM2: [16x128] @ [128x64]
  bf16x8 a2[4];
#pragma unroll
  for (int kt = 0; kt < 4; ++kt)
    a2[kt] = *(const bf16x8*)&Hs[(m0 + c) * 136 + kt * 32 + kc * 8];
#pragma unroll
  for (int nt2 = 0; nt2 < 4; ++nt2) {
    float bv = b2[nt2 * 16 + c];
    f32x4 acc = {bv, bv, bv, bv};
#pragma unroll
    for (int kt = 0; kt < 4; ++kt) {
      bf16x8 bf = *(const bf16x8*)&W2p[(nt2 * 4 + kt) * 512 + kc * 128 + c * 8];
      acc = __builtin_amdgcn_mfma_f32_16x16x32_bf16(a2[kt], bf, acc, 0, 0, 0);
    }
#pragma unroll
    for (int r = 0; r < 4; ++r) {
      int g = n0b + m0 + kc * 4 + r;
      if (g < N_NODES) {
        float o = acc[r];
        hout[(size_t)g * 64 + nt2 * 16 + c] = (__bf16)((o > 0.0f) ? o : expm1f(o));
      }
    }
  }
}

// per-graph sum/max/count; batch sorted -> wave scans contiguous chunk
__global__ void pool_kernel(const __bf16* __restrict__ h,
                            const int* __restrict__ batch,
                            float* gsum, unsigned* gmax, int* gcnt) {
  int lane = threadIdx.x & 63;
  int wave = (blockIdx.x * blockDim.x + threadIdx.x) >> 6;
  int nwaves = (gridDim.x * blockDim.x) >> 6;
  int chunk = (N_NODES + nwaves - 1) / nwaves;
  int n0 = wave * chunk;
  int n1 = min(n0 + chunk, N_NODES);
  if (n0 >= N_NODES) return;
  int cur = batch[n0];
  float s = 0.0f, m = -2.0f;
  int cnt = 0;
  for (int n = n0; n < n1; ++n) {
    int g = batch[n];
    if (g != cur) {
      atomicAdd(&gsum[cur * 64 + lane], s);
      atomicMax(&gmax[cur * 64 + lane], f2ord(m));
      if (lane == 0) atomicAdd(&gcnt[cur], cnt);
      cur = g; s = 0.0f; m = -2.0f; cnt = 0;
    }
    float v = (float)h[(size_t)n * 64 + lane];
    s += v;
    m = fmaxf(m, v);
    ++cnt;
  }
  atomicAdd(&gsum[cur * 64 + lane], s);
  atomicMax(&gmax[cur * 64 + lane], f2ord(m));
  if (lane == 0) atomicAdd(&gcnt[cur], cnt);
}

// out = relu([mean|max] @ Wc1 + bc1) @ Wc2 + bc2 ; one 64-thread block / graph
__global__ void cls_kernel(const float* __restrict__ gsum,
                           const unsigned* __restrict__ gmax,
                           const int* __restrict__ gcnt,
                           const float* __restrict__ Wc1,
                           const float* __restrict__ bc1,
                           const float* __restrict__ Wc2,
                           const float* __restrict__ bc2,
                           float* __restrict__ out) {
  __shared__ float gv[128];
  __shared__ float tv[64];
  int g = blockIdx.x, l = threadIdx.x;
  float cnt = fmaxf((float)gcnt[g], 1.0f);
  gv[l] = gsum[g * 64 + l] / cnt;
  gv[64 + l] = ord2f(gmax[g * 64 + l]);
  __syncthreads();
  float acc = bc1[l];
#pragma unroll 8
  for (int k = 0; k < 128; ++k) acc = fmaf(gv[k], Wc1[k * 64 + l], acc);
  tv[l] = fmaxf(acc, 0.0f);
  __syncthreads();
  if (l < 10) {
    float o = bc2[l];
#pragma unroll
    for (int k = 0; k < 64; ++k) o = fmaf(tv[k], Wc2[k * 10 + l], o);
    out[g * 10 + l] = o;
  }
}

extern "C" void kernel_launch(void* const* d_in, const int* in_sizes, int n_in,
                              void* d_out, int out_size, void* d_ws, size_t ws_size,
                              hipStream_t stream) {
  const float* x     = (const float*)d_in[0];
  const int*   ei    = (const int*)d_in[1];
  const int*   batch = (const int*)d_in[2];
  const float* W_emb = (const float*)d_in[3];
  const float* b_emb = (const float*)d_in[4];
  const float* eps1  = (const float*)d_in[5];
  const float* W1a   = (const float*)d_in[6];
  const float* b1a   = (const float*)d_in[7];
  const float* W1b   = (const float*)d_in[8];
  const float* b1b   = (const float*)d_in[9];
  const float* eps2  = (const float*)d_in[10];
  const float* W2a   = (const float*)d_in[11];
  const float* b2a   = (const float*)d_in[12];
  const float* W2b   = (const float*)d_in[13];
  const float* b2b   = (const float*)d_in[14];
  const float* eps3  = (const float*)d_in[15];
  const float* W3a   = (const float*)d_in[16];
  const float* b3a   = (const float*)d_in[17];
  const float* W3b   = (const float*)d_in[18];
  const float* b3b   = (const float*)d_in[19];
  const float* Wc1   = (const float*)d_in[20];
  const float* bc1   = (const float*)d_in[21];
  const float* Wc2   = (const float*)d_in[22];
  const float* bc2   = (const float*)d_in[23];
  float* out = (float*)d_out;

  // workspace layout (byte-based)
  char* w = (char*)d_ws;
  __bf16*   h0   = (__bf16*)w;                     w += (size_t)N_NODES * 64 * 2;  // 12.8MB
  __bf16*   h1   = (__bf16*)w;                     w += (size_t)N_NODES * 64 * 2;  // 12.8MB
  float*    gsum = (float*)w;                      w += N_GRAPHS * 64 * 4;
  unsigned* gmax = (unsigned*)w;                   w += N_GRAPHS * 64 * 4;
  int*      gcnt = (int*)w;                        w += N_GRAPHS * 4;
  __bf16*   wp   = (__bf16*)w;                     w += 3 * 16384 * 2;
  int*      deg  = (int*)w;                        w += (size_t)N_NODES * 4;
  int*      curw = (int*)w;                        w += (size_t)N_NODES * 4;
  int*      rowp = (int*)w;                        w += (size_t)(N_NODES + 1) * 4;
  int*      bsum = (int*)w;                        w += 512 * 4;
  int*      boff = (int*)w;                        w += 512 * 4;
  int*      ssrc = (int*)w;                        w += (size_t)N_EDGES * 4;      // 4.8MB

  const int* src = ei;             // edge_index[0]
  const int* dst = ei + N_EDGES;   // edge_index[1]

  const float* epss[3] = {eps1, eps2, eps3};
  const float* bas[3]  = {b1a, b2a, b3a};
  const float* bbs[3]  = {b1b, b2b, b3b};

  const int NB = (N_NODES + 255) / 256;  // 391
  const int EB = (N_EDGES + 255) / 256;

  // per-node CSR build (edge list identical for all 3 layers)
  hipMemsetAsync(deg, 0, N_NODES * sizeof(int), stream);
  hist_kernel<<<EB, 256, 0, stream>>>(dst, deg);
  scan_sums_kernel<<<NB, 256, 0, stream>>>(deg, bsum);
  scan_bsums_kernel<<<1, 512, 0, stream>>>(bsum, boff, NB);
  scan_final_kernel<<<NB, 256, 0, stream>>>(deg, boff, rowp, curw);
  fill_csr_kernel<<<EB, 256, 0, stream>>>(src, dst, curw, ssrc);

  convert_all_kernel<<<192, 256, 0, stream>>>(W1a, W1b, W2a, W2b, W3a, W3b, wp,
                                              gsum, gmax, gcnt);
  embed_kernel<<<(N_NODES * 64) / 256, 256, 0, stream>>>(x, W_emb, b_emb, h0);

  __bf16* hbuf[4] = {h0, h1, h0, h1};
  for (int L = 0; L < 3; ++L) {
    gin_fused3_kernel<<<(N_NODES + 63) / 64, 256, 0, stream>>>(
        hbuf[L], hbuf[L + 1], rowp, ssrc, epss[L],
        wp + (size_t)L * 16384, bas[L],
        wp + (size_t)L * 16384 + 8192, bbs[L]);
  }

  pool_kernel<<<512, 256, 0, stream>>>(h1, batch, gsum, gmax, gcnt);
  cls_kernel<<<N_GRAPHS, 64, 0, stream>>>(gsum, gmax, gcnt, Wc1, bc1, Wc2, bc2, out);
}

// Round 6
// 423.580 us; speedup vs baseline: 4.5789x; 1.1935x over previous
//
#include <hip/hip_runtime.h>
#include <hip/hip_bf16.h>
#include <math.h>

#define N_NODES 100000
#define N_EDGES 1200000
#define N_GRAPHS 512
#define NBUCKET 98           // ceil(N_NODES / 1024)
#define TILE 2048            // edges per partition tile
#define CSR_CAP 16384        // LDS staging capacity in bucket_csr (mean 12245, sd ~110)

typedef __bf16 bf16x8 __attribute__((ext_vector_type(8)));
typedef float f32x4 __attribute__((ext_vector_type(4)));

// ---- float <-> monotonic unsigned (for atomicMax on floats) ----
__device__ __forceinline__ unsigned f2ord(float f) {
  unsigned u = __float_as_uint(f);
  return (u & 0x80000000u) ? ~u : (u | 0x80000000u);
}
__device__ __forceinline__ float ord2f(unsigned u) {
  return (u & 0x80000000u) ? __uint_as_float(u & 0x7fffffffu) : __uint_as_float(~u);
}

// ---------------- two-level counting-sort CSR build -------------------------
// K1: coarse histogram (bucket = dst >> 10), LDS-aggregated
__global__ void bucket_hist_kernel(const int* __restrict__ dst, int* __restrict__ bcnt) {
  __shared__ int c[128];
  int t = threadIdx.x;
  if (t < 128) c[t] = 0;
  __syncthreads();
  for (int e = blockIdx.x * 256 + t; e < N_EDGES; e += gridDim.x * 256)
    atomicAdd(&c[dst[e] >> 10], 1);
  __syncthreads();
  if (t < NBUCKET && c[t] > 0) atomicAdd(&bcnt[t], c[t]);
}

// K2: exclusive scan of 98 bucket counts; init cursors; rowp[N]=E
__global__ void bucket_scan_kernel(const int* __restrict__ bcnt,
                                   int* __restrict__ bbase,
                                   int* __restrict__ bcursor,
                                   int* __restrict__ rowp) {
  __shared__ int s[128];
  int t = threadIdx.x;  // 128 threads
  int own = (t < NBUCKET) ? bcnt[t] : 0;
  s[t] = own;
  __syncthreads();
  for (int o = 1; o < 128; o <<= 1) {
    int v = (t >= o) ? s[t - o] : 0;
    __syncthreads();
    s[t] += v;
    __syncthreads();
  }
  if (t < NBUCKET) {
    int excl = s[t] - own;
    bbase[t] = excl;
    bcursor[t] = excl;
  }
  if (t == 0) {
    bbase[NBUCKET] = N_EDGES;
    rowp[N_NODES] = N_EDGES;
  }
}

// K3: partition edges into bucket regions with coalesced writes.
// entry = src | (dst & 1023) << 17   (src < 2^17, dst_local < 1024)
__global__ void partition_kernel(const int* __restrict__ src, const int* __restrict__ dst,
                                 int* __restrict__ bcursor, unsigned* __restrict__ ent) {
  __shared__ int cnt[128];
  __shared__ int cnt2[128];
  __shared__ int lstart[128];
  __shared__ int gbase[128];
  __shared__ int s[128];
  __shared__ unsigned sorted[TILE];
  __shared__ unsigned char bid[TILE];
  int t = threadIdx.x;
  int e0 = blockIdx.x * TILE;
  if (t < 128) { cnt[t] = 0; cnt2[t] = 0; }
  __syncthreads();

  unsigned v[8];
  int b[8];
#pragma unroll
  for (int u = 0; u < 8; ++u) {
    int e = e0 + u * 256 + t;
    b[u] = -1;
    if (e < N_EDGES) {
      int d = dst[e];
      b[u] = d >> 10;
      v[u] = (unsigned)src[e] | ((unsigned)(d & 1023) << 17);
      atomicAdd(&cnt[b[u]], 1);
    }
  }
  __syncthreads();
  // exclusive scan of cnt[0..127]
  if (t < 128) s[t] = cnt[t];
  __syncthreads();
  for (int o = 1; o < 128; o <<= 1) {
    int x = (t >= o && t < 128) ? s[t - o] : 0;
    __syncthreads();
    if (t < 128) s[t] += x;
    __syncthreads();
  }
  if (t < 128) lstart[t] = s[t] - cnt[t];
  __syncthreads();
  // reserve global space per bucket
  if (t < NBUCKET) gbase[t] = (cnt[t] > 0) ? atomicAdd(&bcursor[t], cnt[t]) : 0;
  __syncthreads();
  // scatter into LDS, sorted by bucket
#pragma unroll
  for (int u = 0; u < 8; ++u) {
    if (b[u] >= 0) {
      int p = lstart[b[u]] + atomicAdd(&cnt2[b[u]], 1);
      sorted[p] = v[u];
      bid[p] = (unsigned char)b[u];
    }
  }
  __syncthreads();
  // coalesced write-out (consecutive i -> mostly consecutive addresses)
  int ntile = min(TILE, N_EDGES - e0);
  for (int i = t; i < ntile; i += 256) {
    int bb = bid[i];
    ent[gbase[bb] + (i - lstart[bb])] = sorted[i];
  }
}

// K4: per-bucket fine CSR: LDS-staged entries, LDS deg/scan, XCD-local scatter.
__launch_bounds__(256)
__global__ void bucket_csr_kernel(const unsigned* __restrict__ ent,
                                  const int* __restrict__ bbase,
                                  int* __restrict__ rowp,
                                  int* __restrict__ ssrc) {
  __shared__ unsigned le[CSR_CAP];   // 64 KB
  __shared__ int deg[1024];          // also reused as scatter cursor
  __shared__ int excl[1024];
  __shared__ int ws[256];
  int t = threadIdx.x;
  int b = blockIdx.x;
  int base = bbase[b];
  int cntb = bbase[b + 1] - base;
#pragma unroll
  for (int k = 0; k < 4; ++k) deg[t * 4 + k] = 0;
  __syncthreads();
  // stage + histogram
  for (int i = t; i < cntb; i += 256) {
    unsigned e = ent[base + i];
    if (i < CSR_CAP) le[i] = e;
    atomicAdd(&deg[e >> 17], 1);
  }
  __syncthreads();
  // scan 1024 (4 per thread + block scan of 256 partials)
  int d0 = deg[t * 4], d1 = deg[t * 4 + 1], d2 = deg[t * 4 + 2], d3 = deg[t * 4 + 3];
  int sum4 = d0 + d1 + d2 + d3;
  ws[t] = sum4;
  __syncthreads();
  for (int o = 1; o < 256; o <<= 1) {
    int x = (t >= o) ? ws[t - o] : 0;
    __syncthreads();
    ws[t] += x;
    __syncthreads();
  }
  int run = ws[t] - sum4;
  excl[t * 4] = run; run += d0;
  excl[t * 4 + 1] = run; run += d1;
  excl[t * 4 + 2] = run; run += d2;
  excl[t * 4 + 3] = run;
  __syncthreads();
  // rowp + cursor init (deg reused as cursor)
  int node0 = b << 10;
#pragma unroll
  for (int k = 0; k < 4; ++k) {
    int i = t * 4 + k;
    int n = node0 + i;
    if (n < N_NODES) rowp[n] = base + excl[i];
    deg[i] = excl[i];
  }
  __syncthreads();
  // scatter src into bucket-local window (stays in one XCD's L2)
  for (int i = t; i < cntb; i += 256) {
    unsigned e = (i < CSR_CAP) ? le[i] : ent[base + i];
    int p = atomicAdd(&deg[e >> 17], 1);
    ssrc[base + p] = (int)(e & 0x1FFFFu);
  }
}

// ---------------- dense pipeline ---------------------------------------------
// h0 = x @ W_emb + b_emb   (x: [N,7], W: [7,64]) -> bf16
__global__ void embed_kernel(const float* __restrict__ x,
                             const float* __restrict__ W,
                             const float* __restrict__ b,
                             __bf16* __restrict__ h) {
  __shared__ float Ws[7 * 64];
  __shared__ float bs[64];
  int t = threadIdx.x;
  for (int i = t; i < 7 * 64; i += 256) Ws[i] = W[i];
  if (t < 64) bs[t] = b[t];
  __syncthreads();
  int gid = blockIdx.x * 256 + t;
  int n = gid >> 6, f = gid & 63;
  const float* xr = x + n * 7;
  float acc = bs[f];
#pragma unroll
  for (int k = 0; k < 7; ++k) acc = fmaf(xr[k], Ws[k * 64 + f], acc);
  h[gid] = (__bf16)acc;
}

// Pre-permute all 3 layers' weights into bf16 MFMA B-fragment order;
// also folds the pool-accumulator init.
__global__ void convert_all_kernel(const float* __restrict__ W1a, const float* __restrict__ W1b,
                                   const float* __restrict__ W2a, const float* __restrict__ W2b,
                                   const float* __restrict__ W3a, const float* __restrict__ W3b,
                                   __bf16* __restrict__ wp,
                                   float* gsum, unsigned* gmax, int* gcnt) {
  int o = blockIdx.x * 256 + threadIdx.x;  // 0..49151
  if (o < N_GRAPHS * 64) {
    gsum[o] = 0.0f;
    gmax[o] = 0x407FFFFFu;  // f2ord(-1.0f); elu outputs > -1, safe identity
  }
  if (o < N_GRAPHS) gcnt[o] = 0;
  int L = o >> 14, q = o & 16383;
  const float* Wa = (L == 0) ? W1a : (L == 1) ? W2a : W3a;
  const float* Wb = (L == 0) ? W1b : (L == 1) ? W2b : W3b;
  if (q < 8192) {
    int j = q & 7, c = (q >> 3) & 15, kc = (q >> 7) & 3, kt = (q >> 9) & 1, nt = q >> 10;
    wp[o] = (__bf16)Wa[(kt * 32 + kc * 8 + j) * 128 + nt * 16 + c];
  } else {
    int p = q - 8192;
    int j = p & 7, c = (p >> 3) & 15, kc = (p >> 7) & 3, kt = (p >> 9) & 3, nt2 = p >> 11;
    wp[o] = (__bf16)Wb[(kt * 32 + kc * 8 + j) * 64 + nt2 * 16 + c];
  }
}

// Fused: CSR gather (row-serial register accumulation, dual-row interleave,
// scalar src indices) + GIN MLP via MFMA. One block = 64 nodes, 4 waves;
// each wave owns rows wv*16..+15 end-to-end -> NO __syncthreads.
__launch_bounds__(256)
__global__ void gin_fused3_kernel(const __bf16* __restrict__ hin,
                                  __bf16* __restrict__ hout,
                                  const int* __restrict__ row_ptr,
                                  const int* __restrict__ ssrc,
                                  const float* __restrict__ eps_p,
                                  const __bf16* __restrict__ W1p,
                                  const float* __restrict__ b1,
                                  const __bf16* __restrict__ W2p,
                                  const float* __restrict__ b2) {
  __shared__ __bf16 As[64 * 72];
  __shared__ __bf16 Hs[64 * 136];
  int t = threadIdx.x, lane = t & 63, wv = t >> 6;
  int c = lane & 15, kc = lane >> 4;
  int m0 = wv * 16;
  float epsv = 1.0f + eps_p[0];
  int n0b = blockIdx.x * 64;
  int n0w = n0b + m0;

  // row_ptr[n0w .. n0w+16] via lanes 0..16
  int rp = row_ptr[min(n0w + min(lane, 16), N_NODES)];

  // dual-stream gather: rows (rr, rr+8) with 8 loads in flight
  for (int rr = 0; rr < 8; ++rr) {
    int rA = rr, rB = rr + 8;
    int nA = n0w + rA, nB = n0w + rB;
    int jA = __builtin_amdgcn_readfirstlane(__shfl(rp, rA));
    int eA = __builtin_amdgcn_readfirstlane(__shfl(rp, rA + 1));
    int jB = __builtin_amdgcn_readfirstlane(__shfl(rp, rB));
    int eB = __builtin_amdgcn_readfirstlane(__shfl(rp, rB + 1));
    float accA = (nA < N_NODES) ? epsv * (float)hin[(size_t)nA * 64 + lane] : 0.0f;
    float accB = (nB < N_NODES) ? epsv * (float)hin[(size_t)nB * 64 + lane] : 0.0f;
    while (jA + 4 <= eA && jB + 4 <= eB) {
      int a0 = ssrc[jA], a1 = ssrc[jA + 1], a2 = ssrc[jA + 2], a3 = ssrc[jA + 3];
      int b0 = ssrc[jB], b1_ = ssrc[jB + 1], b2_ = ssrc[jB + 2], b3_ = ssrc[jB + 3];
      float fa0 = (float)hin[(size_t)a0 * 64 + lane];
      float fa1 = (float)hin[(size_t)a1 * 64 + lane];
      float fa2 = (float)hin[(size_t)a2 * 64 + lane];
      float fa3 = (float)hin[(size_t)a3 * 64 + lane];
      float fb0 = (float)hin[(size_t)b0 * 64 + lane];
      float fb1 = (float)hin[(size_t)b1_ * 64 + lane];
      float fb2 = (float)hin[(size_t)b2_ * 64 + lane];
      float fb3 = (float)hin[(size_t)b3_ * 64 + lane];
      accA += (fa0 + fa1) + (fa2 + fa3);
      accB += (fb0 + fb1) + (fb2 + fb3);
      jA += 4; jB += 4;
    }
    for (; jA + 4 <= eA; jA += 4) {
      int a0 = ssrc[jA], a1 = ssrc[jA + 1], a2 = ssrc[jA + 2], a3 = ssrc[jA + 3];
      float f0 = (float)hin[(size_t)a0 * 64 + lane];
      float f1 = (float)hin[(size_t)a1 * 64 + lane];
      float f2 = (float)hin[(size_t)a2 * 64 + lane];
      float f3 = (float)hin[(size_t)a3 * 64 + lane];
      accA += (f0 + f1) + (f2 + f3);
    }
    for (; jB + 4 <= eB; jB += 4) {
      int b0 = ssrc[jB], b1v = ssrc[jB + 1], b2v = ssrc[jB + 2], b3v = ssrc[jB + 3];
      float f0 = (float)hin[(size_t)b0 * 64 + lane];
      float f1 = (float)hin[(size_t)b1v * 64 + lane];
      float f2 = (float)hin[(size_t)b2v * 64 + lane];
      float f3 = (float)hin[(size_t)b3v * 64 + lane];
      accB += (f0 + f1) + (f2 + f3);
    }
    for (; jA < eA; ++jA) accA += (float)hin[(size_t)ssrc[jA] * 64 + lane];
    for (; jB < eB; ++jB) accB += (float)hin[(size_t)ssrc[jB] * 64 + lane];
    As[(m0 + rA) * 72 + lane] = (__bf16)accA;
    As[(m0 + rB) * 72 + lane] = (__bf16)accB;
  }

  // GEMM1: [16x64] @ [64x128]  (wave-private rows)
  bf16x8 a1_0 = *(const bf16x8*)&As[(m0 + c) * 72 + 0 * 32 + kc * 8];
  bf16x8 a1_1 = *(const bf16x8*)&As[(m0 + c) * 72 + 1 * 32 + kc * 8];
  f32x4 acc1[8];
#pragma unroll
  for (int nt = 0; nt < 8; ++nt) {
    float bv = b1[nt * 16 + c];
    f32x4 acc = {bv, bv, bv, bv};
    bf16x8 bf0 = *(const bf16x8*)&W1p[(nt * 2 + 0) * 512 + kc * 128 + c * 8];
    bf16x8 bf1 = *(const bf16x8*)&W1p[(nt * 2 + 1) * 512 + kc * 128 + c * 8];
    acc = __builtin_amdgcn_mfma_f32_16x16x32_bf16(a1_0, bf0, acc, 0, 0, 0);
    acc = __builtin_amdgcn_mfma_f32_16x16x32_bf16(a1_1, bf1, acc, 0, 0, 0);
    acc1[nt] = acc;
  }
  // relu -> bf16 hidden tile (wave-private rows)
#pragma unroll
  for (int nt = 0; nt < 8; ++nt) {
#pragma unroll
    for (int r = 0; r < 4; ++r) {
      Hs[(m0 + kc * 4 + r) * 136 + nt * 16 + c] = (__bf16)fmaxf(acc1[nt][r], 0.0f);
    }
  }

  // GEMM2: [16x128] @ [128x64]
  bf16x8 a2[4];
#pragma unroll
  for (int kt = 0; kt < 4; ++kt)
    a2[kt] = *(const bf16x8*)&Hs[(m0 + c) * 136 + kt * 32 + kc * 8];
#pragma unroll
  for (int nt2 = 0; nt2 < 4; ++nt2) {
    float bv = b2[nt2 * 16 + c];
    f32x4 acc = {bv, bv, bv, bv};
#pragma unroll
    for (int kt = 0; kt < 4; ++kt) {
      bf16x8 bf = *(const bf16x8*)&W2p[(nt2 * 4 + kt) * 512 + kc * 128 + c * 8];
      acc = __builtin_amdgcn_mfma_f32_16x16x32_bf16(a2[kt], bf, acc, 0, 0, 0);
    }
#pragma unroll
    for (int r = 0; r < 4; ++r) {
      int g = n0b + m0 + kc * 4 + r;
      if (g < N_NODES) {
        float o = acc[r];
        hout[(size_t)g * 64 + nt2 * 16 + c] = (__bf16)((o > 0.0f) ? o : expm1f(o));
      }
    }
  }
}

// per-graph sum/max/count; batch sorted -> wave scans contiguous chunk
__global__ void pool_kernel(const __bf16* __restrict__ h,
                            const int* __restrict__ batch,
                            float* gsum, unsigned* gmax, int* gcnt) {
  int lane = threadIdx.x & 63;
  int wave = (blockIdx.x * blockDim.x + threadIdx.x) >> 6;
  int nwaves = (gridDim.x * blockDim.x) >> 6;
  int chunk = (N_NODES + nwaves - 1) / nwaves;
  int n0 = wave * chunk;
  int n1 = min(n0 + chunk, N_NODES);
  if (n0 >= N_NODES) return;
  int cur = batch[n0];
  float s = 0.0f, m = -2.0f;
  int cnt = 0;
  for (int n = n0; n < n1; ++n) {
    int g = batch[n];
    if (g != cur) {
      atomicAdd(&gsum[cur * 64 + lane], s);
      atomicMax(&gmax[cur * 64 + lane], f2ord(m));
      if (lane == 0) atomicAdd(&gcnt[cur], cnt);
      cur = g; s = 0.0f; m = -2.0f; cnt = 0;
    }
    float v = (float)h[(size_t)n * 64 + lane];
    s += v;
    m = fmaxf(m, v);
    ++cnt;
  }
  atomicAdd(&gsum[cur * 64 + lane], s);
  atomicMax(&gmax[cur * 64 + lane], f2ord(m));
  if (lane == 0) atomicAdd(&gcnt[cur], cnt);
}

// out = relu([mean|max] @ Wc1 + bc1) @ Wc2 + bc2 ; one 64-thread block / graph
__global__ void cls_kernel(const float* __restrict__ gsum,
                           const unsigned* __restrict__ gmax,
                           const int* __restrict__ gcnt,
                           const float* __restrict__ Wc1,
                           const float* __restrict__ bc1,
                           const float* __restrict__ Wc2,
                           const float* __restrict__ bc2,
                           float* __restrict__ out) {
  __shared__ float gv[128];
  __shared__ float tv[64];
  int g = blockIdx.x, l = threadIdx.x;
  float cnt = fmaxf((float)gcnt[g], 1.0f);
  gv[l] = gsum[g * 64 + l] / cnt;
  gv[64 + l] = ord2f(gmax[g * 64 + l]);
  __syncthreads();
  float acc = bc1[l];
#pragma unroll 8
  for (int k = 0; k < 128; ++k) acc = fmaf(gv[k], Wc1[k * 64 + l], acc);
  tv[l] = fmaxf(acc, 0.0f);
  __syncthreads();
  if (l < 10) {
    float o = bc2[l];
#pragma unroll
    for (int k = 0; k < 64; ++k) o = fmaf(tv[k], Wc2[k * 10 + l], o);
    out[g * 10 + l] = o;
  }
}

extern "C" void kernel_launch(void* const* d_in, const int* in_sizes, int n_in,
                              void* d_out, int out_size, void* d_ws, size_t ws_size,
                              hipStream_t stream) {
  const float* x     = (const float*)d_in[0];
  const int*   ei    = (const int*)d_in[1];
  const int*   batch = (const int*)d_in[2];
  const float* W_emb = (const float*)d_in[3];
  const float* b_emb = (const float*)d_in[4];
  const float* eps1  = (const float*)d_in[5];
  const float* W1a   = (const float*)d_in[6];
  const float* b1a   = (const float*)d_in[7];
  const float* W1b   = (const float*)d_in[8];
  const float* b1b   = (const float*)d_in[9];
  const float* eps2  = (const float*)d_in[10];
  const float* W2a   = (const float*)d_in[11];
  const float* b2a   = (const float*)d_in[12];
  const float* W2b   = (const float*)d_in[13];
  const float* b2b   = (const float*)d_in[14];
  const float* eps3  = (const float*)d_in[15];
  const float* W3a   = (const float*)d_in[16];
  const float* b3a   = (const float*)d_in[17];
  const float* W3b   = (const float*)d_in[18];
  const float* b3b   = (const float*)d_in[19];
  const float* Wc1   = (const float*)d_in[20];
  const float* bc1   = (const float*)d_in[21];
  const float* Wc2   = (const float*)d_in[22];
  const float* bc2   = (const float*)d_in[23];
  float* out = (float*)d_out;

  // workspace layout (byte-based)
  char* w = (char*)d_ws;
  __bf16*   h0   = (__bf16*)w;                     w += (size_t)N_NODES * 64 * 2;  // 12.8MB
  __bf16*   h1   = (__bf16*)w;                     w += (size_t)N_NODES * 64 * 2;  // 12.8MB
  float*    gsum = (float*)w;                      w += N_GRAPHS * 64 * 4;
  unsigned* gmax = (unsigned*)w;                   w += N_GRAPHS * 64 * 4;
  int*      gcnt = (int*)w;                        w += N_GRAPHS * 4;
  __bf16*   wp   = (__bf16*)w;                     w += 3 * 16384 * 2;
  int*      bcnt = (int*)w;                        w += 128 * 4;
  int*      bbase= (int*)w;                        w += 136 * 4;
  int*      bcur = (int*)w;                        w += 128 * 4;
  int*      rowp = (int*)w;                        w += (size_t)(N_NODES + 1) * 4;
  unsigned* ent  = (unsigned*)w;                   w += (size_t)N_EDGES * 4;      // 4.8MB
  int*      ssrc = (int*)w;                        w += (size_t)N_EDGES * 4;      // 4.8MB

  const int* src = ei;             // edge_index[0]
  const int* dst = ei + N_EDGES;   // edge_index[1]

  const float* epss[3] = {eps1, eps2, eps3};
  const float* bas[3]  = {b1a, b2a, b3a};
  const float* bbs[3]  = {b1b, b2b, b3b};

  // ---- CSR build via two-level counting sort (edge list shared by layers) --
  hipMemsetAsync(bcnt, 0, 128 * sizeof(int), stream);
  bucket_hist_kernel<<<256, 256, 0, stream>>>(dst, bcnt);
  bucket_scan_kernel<<<1, 128, 0, stream>>>(bcnt, bbase, bcur, rowp);
  partition_kernel<<<(N_EDGES + TILE - 1) / TILE, 256, 0, stream>>>(src, dst, bcur, ent);
  bucket_csr_kernel<<<NBUCKET, 256, 0, stream>>>(ent, bbase, rowp, ssrc);

  convert_all_kernel<<<192, 256, 0, stream>>>(W1a, W1b, W2a, W2b, W3a, W3b, wp,
                                              gsum, gmax, gcnt);
  embed_kernel<<<(N_NODES * 64) / 256, 256, 0, stream>>>(x, W_emb, b_emb, h0);

  __bf16* hbuf[4] = {h0, h1, h0, h1};
  for (int L = 0; L < 3; ++L) {
    gin_fused3_kernel<<<(N_NODES + 63) / 64, 256, 0, stream>>>(
        hbuf[L], hbuf[L + 1], rowp, ssrc, epss[L],
        wp + (size_t)L * 16384, bas[L],
        wp + (size_t)L * 16384 + 8192, bbs[L]);
  }

  pool_kernel<<<512, 256, 0, stream>>>(h1, batch, gsum, gmax, gcnt);
  cls_kernel<<<N_GRAPHS, 64, 0, stream>>>(gsum, gmax, gcnt, Wc1, bc1, Wc2, bc2, out);
}